// Round 5
// baseline (6613.449 us; speedup 1.0000x reference)
//
#include <hip/hip_runtime.h>
#include <cstddef>

#define BATCH 8
#define NPTS 8192
#define NFEAT 64
#define NPOINT 2048
#define NSAMPLE 32

// -- plain-rounded ops, contraction-proof (hipcc defaults -ffp-contract=fast;
//    the empty asm blocks mul->fma fusion, matching numpy's non-FMA ufuncs)
__device__ __forceinline__ float sq_nc(float a) {
    float r = a * a;
    asm volatile("" : "+v"(r));
    return r;
}
__device__ __forceinline__ float mul_nc(float a, float b) {
    float r = a * b;
    asm volatile("" : "+v"(r));
    return r;
}

// ---------------------------------------------------------------------------
// FPS: one block per batch, 1024 threads, 8 points/thread.
// d = (dx*dx + dy*dy) + dz*dz, ALL plain rounded (numpy separate-ufunc
// semantics: subtract/square/add.reduce -> no contraction).  [verified R4]
// argmax tie-break: smallest index (np.argmax first-occurrence).
// ---------------------------------------------------------------------------
__global__ __launch_bounds__(1024) void fps_kernel(const float* __restrict__ xyz,
                                                   float* __restrict__ newxyz) {
    extern __shared__ float lds[];
    float* sx = lds;
    float* sy = lds + NPTS;
    float* sz = lds + 2 * NPTS;
    float* red_v = lds + 3 * NPTS;          // 16 floats
    int*   red_i = (int*)(lds + 3 * NPTS + 16);
    int*   s_last = (int*)(lds + 3 * NPTS + 32);

    const int b = blockIdx.x;
    const int tid = threadIdx.x;
    const int lane = tid & 63;
    const int wid = tid >> 6;
    const float* xb = xyz + (size_t)b * NPTS * 3;

    float mx[8], my_[8], mz[8], md[8];
#pragma unroll
    for (int j = 0; j < 8; ++j) {
        int i = j * 1024 + tid;
        float x = xb[i * 3 + 0], y = xb[i * 3 + 1], z = xb[i * 3 + 2];
        sx[i] = x; sy[i] = y; sz[i] = z;
        mx[j] = x; my_[j] = y; mz[j] = z;
        md[j] = INFINITY;
    }
    __syncthreads();
    if (tid == 0) {
        newxyz[(size_t)b * NPOINT * 3 + 0] = sx[0];
        newxyz[(size_t)b * NPOINT * 3 + 1] = sy[0];
        newxyz[(size_t)b * NPOINT * 3 + 2] = sz[0];
    }
    int last = 0;
    for (int it = 1; it < NPOINT; ++it) {
        float xl = sx[last], yl = sy[last], zl = sz[last];
        float bv = -1.0f; int bi = 0x7fffffff;
#pragma unroll
        for (int j = 0; j < 8; ++j) {
            float dx = mx[j] - xl;
            float dy = my_[j] - yl;
            float dz = mz[j] - zl;
            float d = (sq_nc(dx) + sq_nc(dy)) + sq_nc(dz);
            float m = fminf(md[j], d);
            md[j] = m;
            int idx = j * 1024 + tid;
            if (m > bv || (m == bv && idx < bi)) { bv = m; bi = idx; }
        }
#pragma unroll
        for (int m = 1; m < 64; m <<= 1) {
            float ov = __shfl_xor(bv, m, 64);
            int   oi = __shfl_xor(bi, m, 64);
            if (ov > bv || (ov == bv && oi < bi)) { bv = ov; bi = oi; }
        }
        if (lane == 0) { red_v[wid] = bv; red_i[wid] = bi; }
        __syncthreads();
        if (tid == 0) {
            float fv = red_v[0]; int fi = red_i[0];
            for (int w = 1; w < 16; ++w) {
                float ov = red_v[w]; int oi = red_i[w];
                if (ov > fv || (ov == fv && oi < fi)) { fv = ov; fi = oi; }
            }
            s_last[0] = fi;
            size_t o = (size_t)b * NPOINT * 3 + (size_t)it * 3;
            newxyz[o + 0] = sx[fi];
            newxyz[o + 1] = sy[fi];
            newxyz[o + 2] = sz[fi];
        }
        __syncthreads();
        last = s_last[0];
    }
}

// ---------------------------------------------------------------------------
// Ball query: first NSAMPLE indices (ascending) with d2 < 0.04f (strict f32).
// d2 = (cq + sq) - 2*dot; cq/sq plain (np.sum separate ufuncs);
// dot = FMA chain (np.einsum K=3 scalar tail in FMA3-dispatched loop):
//       fma(cz,z, fma(cy,y, rn(cx*x))).
// ---------------------------------------------------------------------------
__global__ __launch_bounds__(256) void ball_kernel(const float* __restrict__ xyz,
                                                   const float* __restrict__ newxyz,
                                                   int* __restrict__ ballidx) {
    extern __shared__ float lds[];
    float* sx = lds;
    float* sy = lds + NPTS;
    float* sz = lds + 2 * NPTS;

    const int b = blockIdx.y;
    const int s = blockIdx.x * 256 + threadIdx.x;
    const float* xb = xyz + (size_t)b * NPTS * 3;
    for (int i = threadIdx.x; i < NPTS; i += 256) {
        sx[i] = xb[i * 3 + 0];
        sy[i] = xb[i * 3 + 1];
        sz[i] = xb[i * 3 + 2];
    }
    __syncthreads();

    const int sIdx = b * NPOINT + s;
    float cx = newxyz[(size_t)sIdx * 3 + 0];
    float cy = newxyz[(size_t)sIdx * 3 + 1];
    float cz = newxyz[(size_t)sIdx * 3 + 2];
    float cq = (sq_nc(cx) + sq_nc(cy)) + sq_nc(cz);

    int* ob = ballidx + (size_t)sIdx * NSAMPLE;
    int cnt = 0;
    int first = 0;
    for (int n = 0; n < NPTS; ++n) {
        float x = sx[n], y = sy[n], z = sz[n];
        float sq = (sq_nc(x) + sq_nc(y)) + sq_nc(z);
        float dot = __fmaf_rn(cz, z, __fmaf_rn(cy, y, __fmul_rn(cx, x)));
        float d2 = (cq + sq) - mul_nc(2.0f, dot);
        if (d2 < 0.04f) {
            ob[cnt] = n;
            if (cnt == 0) first = n;
            ++cnt;
            if (cnt == NSAMPLE) break;
        }
    }
    for (int j = cnt; j < NSAMPLE; ++j) ob[j] = first;
}

// ---------------------------------------------------------------------------
// F1 precompute: F1[b,n,c] = sum_{c'} features[b,c',n] * W1[3+c', c]
// (continuous path -> any rounding OK)
// ---------------------------------------------------------------------------
__global__ __launch_bounds__(256) void f1_kernel(const float* __restrict__ features,
                                                 const float* __restrict__ W1,
                                                 float* __restrict__ F1) {
    const int t = blockIdx.x * 256 + threadIdx.x;   // 0 .. BATCH*NPTS-1
    const int b = t >> 13;
    const int n = t & (NPTS - 1);
    const float* fb = features + (size_t)b * NFEAT * NPTS + n;

    float acc[64];
#pragma unroll
    for (int c = 0; c < 64; ++c) acc[c] = 0.0f;

    for (int cp = 0; cp < 64; ++cp) {
        float f = fb[(size_t)cp * NPTS];
        const float4* w = reinterpret_cast<const float4*>(W1 + (size_t)(3 + cp) * 64);
#pragma unroll
        for (int c4 = 0; c4 < 16; ++c4) {
            float4 ww = w[c4];
            acc[c4 * 4 + 0] += f * ww.x;
            acc[c4 * 4 + 1] += f * ww.y;
            acc[c4 * 4 + 2] += f * ww.z;
            acc[c4 * 4 + 3] += f * ww.w;
        }
    }
    float* o = F1 + (size_t)t * 64;
#pragma unroll
    for (int c4 = 0; c4 < 16; ++c4) {
        float4 v;
        v.x = acc[c4 * 4 + 0]; v.y = acc[c4 * 4 + 1];
        v.z = acc[c4 * 4 + 2]; v.w = acc[c4 * 4 + 3];
        *reinterpret_cast<float4*>(o + c4 * 4) = v;
    }
}

// ---------------------------------------------------------------------------
// Fused grouped-MLP + max-pool. 256 threads = 8 centers x 32 samples.
// h1/h2 in registers (compile-time indexing, no LDS).
// ---------------------------------------------------------------------------
__global__ __launch_bounds__(256) void mlp_kernel(const float* __restrict__ xyz,
                                                  const float* __restrict__ W1,
                                                  const float* __restrict__ b1,
                                                  const float* __restrict__ W2,
                                                  const float* __restrict__ b2,
                                                  const float* __restrict__ W3,
                                                  const float* __restrict__ b3,
                                                  const float* __restrict__ F1,
                                                  const int* __restrict__ ballidx,
                                                  const float* __restrict__ newxyz,
                                                  float* __restrict__ outF) {
    const int tid = threadIdx.x;
    const int k = tid & 31;
    const int g = tid >> 5;
    const int sIdx = blockIdx.x * 8 + g;          // 0 .. BATCH*NPOINT-1
    const int b = sIdx >> 11;
    const int s = sIdx & (NPOINT - 1);

    const int p = ballidx[(size_t)sIdx * NSAMPLE + k];
    const float* xb = xyz + (size_t)b * NPTS * 3;
    float rx = xb[p * 3 + 0] - newxyz[(size_t)sIdx * 3 + 0];
    float ry = xb[p * 3 + 1] - newxyz[(size_t)sIdx * 3 + 1];
    float rz = xb[p * 3 + 2] - newxyz[(size_t)sIdx * 3 + 2];

    // ---- layer 1: h1 in registers
    float h1[64];
    const float* f1p = F1 + ((size_t)b * NPTS + p) * 64;
#pragma unroll
    for (int c4 = 0; c4 < 16; ++c4) {
        float4 f  = *reinterpret_cast<const float4*>(f1p + c4 * 4);
        float4 wx = *reinterpret_cast<const float4*>(W1 + c4 * 4);
        float4 wy = *reinterpret_cast<const float4*>(W1 + 64 + c4 * 4);
        float4 wz = *reinterpret_cast<const float4*>(W1 + 128 + c4 * 4);
        float4 bb = *reinterpret_cast<const float4*>(b1 + c4 * 4);
        h1[c4 * 4 + 0] = fmaxf(bb.x + f.x + rx * wx.x + ry * wy.x + rz * wz.x, 0.0f);
        h1[c4 * 4 + 1] = fmaxf(bb.y + f.y + rx * wx.y + ry * wy.y + rz * wz.y, 0.0f);
        h1[c4 * 4 + 2] = fmaxf(bb.z + f.z + rx * wx.z + ry * wy.z + rz * wz.z, 0.0f);
        h1[c4 * 4 + 3] = fmaxf(bb.w + f.w + rx * wx.w + ry * wy.w + rz * wz.w, 0.0f);
    }

    // ---- layer 2: h2 in registers
    float h2[64];
#pragma unroll
    for (int d4 = 0; d4 < 16; ++d4) {
        float4 bb = *reinterpret_cast<const float4*>(b2 + d4 * 4);
        h2[d4 * 4 + 0] = bb.x; h2[d4 * 4 + 1] = bb.y;
        h2[d4 * 4 + 2] = bb.z; h2[d4 * 4 + 3] = bb.w;
    }
#pragma unroll
    for (int c = 0; c < 64; ++c) {
        float a = h1[c];
        const float4* w = reinterpret_cast<const float4*>(W2 + (size_t)c * 64);
#pragma unroll
        for (int d4 = 0; d4 < 16; ++d4) {
            float4 ww = w[d4];
            h2[d4 * 4 + 0] += a * ww.x;
            h2[d4 * 4 + 1] += a * ww.y;
            h2[d4 * 4 + 2] += a * ww.z;
            h2[d4 * 4 + 3] += a * ww.w;
        }
    }
#pragma unroll
    for (int d = 0; d < 64; ++d) h2[d] = fmaxf(h2[d], 0.0f);

    // ---- layer 3 + relu + max over 32 samples, 4 chunks of 32 channels
    const size_t obase = (size_t)b * 128 * NPOINT + s;
#pragma unroll 1
    for (int ch = 0; ch < 4; ++ch) {
        float acc[32];
#pragma unroll
        for (int j4 = 0; j4 < 8; ++j4) {
            float4 bb = *reinterpret_cast<const float4*>(b3 + ch * 32 + j4 * 4);
            acc[j4 * 4 + 0] = bb.x; acc[j4 * 4 + 1] = bb.y;
            acc[j4 * 4 + 2] = bb.z; acc[j4 * 4 + 3] = bb.w;
        }
#pragma unroll
        for (int c = 0; c < 64; ++c) {
            float a = h2[c];
            const float4* w = reinterpret_cast<const float4*>(W3 + (size_t)c * 128 + ch * 32);
#pragma unroll
            for (int j4 = 0; j4 < 8; ++j4) {
                float4 ww = w[j4];
                acc[j4 * 4 + 0] += a * ww.x;
                acc[j4 * 4 + 1] += a * ww.y;
                acc[j4 * 4 + 2] += a * ww.z;
                acc[j4 * 4 + 3] += a * ww.w;
            }
        }
#pragma unroll
        for (int j = 0; j < 32; ++j) {
            float v = fmaxf(acc[j], 0.0f);
#pragma unroll
            for (int m = 16; m >= 1; m >>= 1) v = fmaxf(v, __shfl_xor(v, m, 64));
            acc[j] = v;
        }
        if (k == 0) {
#pragma unroll
            for (int j = 0; j < 32; ++j)
                outF[obase + (size_t)(ch * 32 + j) * NPOINT] = acc[j];
        }
    }
}

// ---------------------------------------------------------------------------
extern "C" void kernel_launch(void* const* d_in, const int* in_sizes, int n_in,
                              void* d_out, int out_size, void* d_ws, size_t ws_size,
                              hipStream_t stream) {
    const float* xyz      = (const float*)d_in[0];
    const float* features = (const float*)d_in[1];
    const float* W1       = (const float*)d_in[2];
    const float* b1       = (const float*)d_in[3];
    const float* W2       = (const float*)d_in[4];
    const float* b2       = (const float*)d_in[5];
    const float* W3       = (const float*)d_in[6];
    const float* b3       = (const float*)d_in[7];

    float* out_newxyz = (float*)d_out;                                  // B*NPOINT*3 f32
    float* out_feat   = (float*)d_out + (size_t)BATCH * NPOINT * 3;     // B*128*NPOINT f32

    // workspace: ballidx 2MB | F1 16.8MB
    int*   ballidx = (int*)d_ws;
    float* F1      = (float*)((char*)d_ws + (size_t)BATCH * NPOINT * NSAMPLE * 4);

    f1_kernel<<<(BATCH * NPTS) / 256, 256, 0, stream>>>(features, W1, F1);

    fps_kernel<<<BATCH, 1024, 3 * NPTS * 4 + 256, stream>>>(xyz, out_newxyz);

    ball_kernel<<<dim3(NPOINT / 256, BATCH), 256, 3 * NPTS * 4, stream>>>(xyz, out_newxyz, ballidx);

    mlp_kernel<<<(BATCH * NPOINT) / 8, 256, 0, stream>>>(
        xyz, W1, b1, W2, b2, W3, b3, F1, ballidx, out_newxyz, out_feat);
}

// Round 6
// 3360.740 us; speedup vs baseline: 1.9679x; 1.9679x over previous
//
#include <hip/hip_runtime.h>
#include <cstddef>

#define BATCH 8
#define NPTS 8192
#define NFEAT 64
#define NPOINT 2048
#define NSAMPLE 32

// -- plain-rounded ops, contraction-proof (hipcc defaults -ffp-contract=fast;
//    the empty asm blocks mul->fma fusion, matching numpy's non-FMA ufuncs)
__device__ __forceinline__ float sq_nc(float a) {
    float r = a * a;
    asm volatile("" : "+v"(r));
    return r;
}
__device__ __forceinline__ float mul_nc(float a, float b) {
    float r = a * b;
    asm volatile("" : "+v"(r));
    return r;
}

// ---------------------------------------------------------------------------
// FPS: one block per batch, 512 threads, 16 points/thread in registers.
// d = (dx*dx + dy*dy) + dz*dz, ALL plain rounded (verified bit-exact R4/R5).
// Point idx = tid*16 + j (thread-contiguous). argmax tie-break = smallest
// global index, via packed u64 (bits(v)<<32)|~idx and max-reduction.
// ONE barrier per iteration (parity double-buffered reduction scratch);
// final 8-way reduce done redundantly by all threads (no serial tail).
// ---------------------------------------------------------------------------
__global__ __launch_bounds__(512) void fps_kernel(const float* __restrict__ xyz,
                                                  float* __restrict__ newxyz) {
    extern __shared__ float lds[];
    float* sx = lds;
    float* sy = lds + NPTS;
    float* sz = lds + 2 * NPTS;
    __shared__ alignas(16) unsigned long long redp[2][8];

    const int b = blockIdx.x;
    const int tid = threadIdx.x;
    const int lane = tid & 63;
    const int wid = tid >> 6;
    const float* xb = xyz + (size_t)b * NPTS * 3;

    // coalesced global -> LDS staging
    for (int i = tid; i < NPTS; i += 512) {
        sx[i] = xb[i * 3 + 0];
        sy[i] = xb[i * 3 + 1];
        sz[i] = xb[i * 3 + 2];
    }
    __syncthreads();

    // per-thread register tiles (one-time LDS reads, conflicts irrelevant)
    float mx[16], my_[16], mz[16], md[16];
    const int base = tid * 16;
#pragma unroll
    for (int j = 0; j < 16; ++j) {
        mx[j] = sx[base + j];
        my_[j] = sy[base + j];
        mz[j] = sz[base + j];
        md[j] = INFINITY;
    }

    if (tid == 0) {
        newxyz[(size_t)b * NPOINT * 3 + 0] = sx[0];
        newxyz[(size_t)b * NPOINT * 3 + 1] = sy[0];
        newxyz[(size_t)b * NPOINT * 3 + 2] = sz[0];
    }

    float xl = sx[0], yl = sy[0], zl = sz[0];
    int par = 0;

    for (int it = 1; it < NPOINT; ++it) {
        // ---- update md + local argmax (ascending j, strict > => first max)
        float bv = -1.0f;
        int bi = 0;
#pragma unroll
        for (int j = 0; j < 16; ++j) {
            float dx = mx[j] - xl;
            float dy = my_[j] - yl;
            float dz = mz[j] - zl;
            float d = (sq_nc(dx) + sq_nc(dy)) + sq_nc(dz);
            float m = fminf(md[j], d);
            md[j] = m;
            if (m > bv) { bv = m; bi = base + j; }
        }

        // ---- pack (value, ~idx) into u64; max == (max value, min idx)
        unsigned long long pk =
            ((unsigned long long)__float_as_uint(bv) << 32) | (unsigned int)(~(unsigned int)bi);

        // ---- wave butterfly max (6 steps)
#pragma unroll
        for (int m = 1; m < 64; m <<= 1) {
            unsigned long long o = __shfl_xor(pk, m, 64);
            pk = (o > pk) ? o : pk;
        }
        if (lane == 0) redp[par][wid] = pk;
        __syncthreads();

        // ---- all threads redundantly reduce the 8 wave-results
        const ulonglong2* rp = (const ulonglong2*)redp[par];
        ulonglong2 r0 = rp[0], r1 = rp[1], r2 = rp[2], r3 = rp[3];
        unsigned long long m0 = (r0.x > r0.y) ? r0.x : r0.y;
        unsigned long long m1 = (r1.x > r1.y) ? r1.x : r1.y;
        unsigned long long m2 = (r2.x > r2.y) ? r2.x : r2.y;
        unsigned long long m3 = (r3.x > r3.y) ? r3.x : r3.y;
        m0 = (m1 > m0) ? m1 : m0;
        m2 = (m3 > m2) ? m3 : m2;
        m0 = (m2 > m0) ? m2 : m0;
        const int fi = (int)(~(unsigned int)m0);

        xl = sx[fi]; yl = sy[fi]; zl = sz[fi];
        if (tid == 0) {
            size_t o = (size_t)b * NPOINT * 3 + (size_t)it * 3;
            newxyz[o + 0] = xl;
            newxyz[o + 1] = yl;
            newxyz[o + 2] = zl;
        }
        par ^= 1;
    }
}

// ---------------------------------------------------------------------------
// Ball query: first NSAMPLE indices (ascending) with d2 < 0.04f (strict f32).
// d2 = (cq + sq) - 2*dot; cq/sq plain (np.sum separate ufuncs);
// dot = FMA chain: fma(cz,z, fma(cy,y, rn(cx*x))).  [verified R5]
// ---------------------------------------------------------------------------
__global__ __launch_bounds__(256) void ball_kernel(const float* __restrict__ xyz,
                                                   const float* __restrict__ newxyz,
                                                   int* __restrict__ ballidx) {
    extern __shared__ float lds[];
    float* sx = lds;
    float* sy = lds + NPTS;
    float* sz = lds + 2 * NPTS;

    const int b = blockIdx.y;
    const int s = blockIdx.x * 256 + threadIdx.x;
    const float* xb = xyz + (size_t)b * NPTS * 3;
    for (int i = threadIdx.x; i < NPTS; i += 256) {
        sx[i] = xb[i * 3 + 0];
        sy[i] = xb[i * 3 + 1];
        sz[i] = xb[i * 3 + 2];
    }
    __syncthreads();

    const int sIdx = b * NPOINT + s;
    float cx = newxyz[(size_t)sIdx * 3 + 0];
    float cy = newxyz[(size_t)sIdx * 3 + 1];
    float cz = newxyz[(size_t)sIdx * 3 + 2];
    float cq = (sq_nc(cx) + sq_nc(cy)) + sq_nc(cz);

    int* ob = ballidx + (size_t)sIdx * NSAMPLE;
    int cnt = 0;
    int first = 0;
    for (int n = 0; n < NPTS; ++n) {
        float x = sx[n], y = sy[n], z = sz[n];
        float sq = (sq_nc(x) + sq_nc(y)) + sq_nc(z);
        float dot = __fmaf_rn(cz, z, __fmaf_rn(cy, y, __fmul_rn(cx, x)));
        float d2 = (cq + sq) - mul_nc(2.0f, dot);
        if (d2 < 0.04f) {
            ob[cnt] = n;
            if (cnt == 0) first = n;
            ++cnt;
            if (cnt == NSAMPLE) break;
        }
    }
    for (int j = cnt; j < NSAMPLE; ++j) ob[j] = first;
}

// ---------------------------------------------------------------------------
// F1 precompute: F1[b,n,c] = sum_{c'} features[b,c',n] * W1[3+c', c]
// ---------------------------------------------------------------------------
__global__ __launch_bounds__(256) void f1_kernel(const float* __restrict__ features,
                                                 const float* __restrict__ W1,
                                                 float* __restrict__ F1) {
    const int t = blockIdx.x * 256 + threadIdx.x;   // 0 .. BATCH*NPTS-1
    const int b = t >> 13;
    const int n = t & (NPTS - 1);
    const float* fb = features + (size_t)b * NFEAT * NPTS + n;

    float acc[64];
#pragma unroll
    for (int c = 0; c < 64; ++c) acc[c] = 0.0f;

    for (int cp = 0; cp < 64; ++cp) {
        float f = fb[(size_t)cp * NPTS];
        const float4* w = reinterpret_cast<const float4*>(W1 + (size_t)(3 + cp) * 64);
#pragma unroll
        for (int c4 = 0; c4 < 16; ++c4) {
            float4 ww = w[c4];
            acc[c4 * 4 + 0] += f * ww.x;
            acc[c4 * 4 + 1] += f * ww.y;
            acc[c4 * 4 + 2] += f * ww.z;
            acc[c4 * 4 + 3] += f * ww.w;
        }
    }
    float* o = F1 + (size_t)t * 64;
#pragma unroll
    for (int c4 = 0; c4 < 16; ++c4) {
        float4 v;
        v.x = acc[c4 * 4 + 0]; v.y = acc[c4 * 4 + 1];
        v.z = acc[c4 * 4 + 2]; v.w = acc[c4 * 4 + 3];
        *reinterpret_cast<float4*>(o + c4 * 4) = v;
    }
}

// ---------------------------------------------------------------------------
// Fused grouped-MLP + max-pool. 256 threads = 8 centers x 32 samples.
// h1/h2 in registers (compile-time indexing, no LDS).
// ---------------------------------------------------------------------------
__global__ __launch_bounds__(256) void mlp_kernel(const float* __restrict__ xyz,
                                                  const float* __restrict__ W1,
                                                  const float* __restrict__ b1,
                                                  const float* __restrict__ W2,
                                                  const float* __restrict__ b2,
                                                  const float* __restrict__ W3,
                                                  const float* __restrict__ b3,
                                                  const float* __restrict__ F1,
                                                  const int* __restrict__ ballidx,
                                                  const float* __restrict__ newxyz,
                                                  float* __restrict__ outF) {
    const int tid = threadIdx.x;
    const int k = tid & 31;
    const int g = tid >> 5;
    const int sIdx = blockIdx.x * 8 + g;          // 0 .. BATCH*NPOINT-1
    const int b = sIdx >> 11;
    const int s = sIdx & (NPOINT - 1);

    const int p = ballidx[(size_t)sIdx * NSAMPLE + k];
    const float* xb = xyz + (size_t)b * NPTS * 3;
    float rx = xb[p * 3 + 0] - newxyz[(size_t)sIdx * 3 + 0];
    float ry = xb[p * 3 + 1] - newxyz[(size_t)sIdx * 3 + 1];
    float rz = xb[p * 3 + 2] - newxyz[(size_t)sIdx * 3 + 2];

    // ---- layer 1: h1 in registers
    float h1[64];
    const float* f1p = F1 + ((size_t)b * NPTS + p) * 64;
#pragma unroll
    for (int c4 = 0; c4 < 16; ++c4) {
        float4 f  = *reinterpret_cast<const float4*>(f1p + c4 * 4);
        float4 wx = *reinterpret_cast<const float4*>(W1 + c4 * 4);
        float4 wy = *reinterpret_cast<const float4*>(W1 + 64 + c4 * 4);
        float4 wz = *reinterpret_cast<const float4*>(W1 + 128 + c4 * 4);
        float4 bb = *reinterpret_cast<const float4*>(b1 + c4 * 4);
        h1[c4 * 4 + 0] = fmaxf(bb.x + f.x + rx * wx.x + ry * wy.x + rz * wz.x, 0.0f);
        h1[c4 * 4 + 1] = fmaxf(bb.y + f.y + rx * wx.y + ry * wy.y + rz * wz.y, 0.0f);
        h1[c4 * 4 + 2] = fmaxf(bb.z + f.z + rx * wx.z + ry * wy.z + rz * wz.z, 0.0f);
        h1[c4 * 4 + 3] = fmaxf(bb.w + f.w + rx * wx.w + ry * wy.w + rz * wz.w, 0.0f);
    }

    // ---- layer 2: h2 in registers
    float h2[64];
#pragma unroll
    for (int d4 = 0; d4 < 16; ++d4) {
        float4 bb = *reinterpret_cast<const float4*>(b2 + d4 * 4);
        h2[d4 * 4 + 0] = bb.x; h2[d4 * 4 + 1] = bb.y;
        h2[d4 * 4 + 2] = bb.z; h2[d4 * 4 + 3] = bb.w;
    }
#pragma unroll
    for (int c = 0; c < 64; ++c) {
        float a = h1[c];
        const float4* w = reinterpret_cast<const float4*>(W2 + (size_t)c * 64);
#pragma unroll
        for (int d4 = 0; d4 < 16; ++d4) {
            float4 ww = w[d4];
            h2[d4 * 4 + 0] += a * ww.x;
            h2[d4 * 4 + 1] += a * ww.y;
            h2[d4 * 4 + 2] += a * ww.z;
            h2[d4 * 4 + 3] += a * ww.w;
        }
    }
#pragma unroll
    for (int d = 0; d < 64; ++d) h2[d] = fmaxf(h2[d], 0.0f);

    // ---- layer 3 + relu + max over 32 samples, 4 chunks of 32 channels
    const size_t obase = (size_t)b * 128 * NPOINT + s;
#pragma unroll 1
    for (int ch = 0; ch < 4; ++ch) {
        float acc[32];
#pragma unroll
        for (int j4 = 0; j4 < 8; ++j4) {
            float4 bb = *reinterpret_cast<const float4*>(b3 + ch * 32 + j4 * 4);
            acc[j4 * 4 + 0] = bb.x; acc[j4 * 4 + 1] = bb.y;
            acc[j4 * 4 + 2] = bb.z; acc[j4 * 4 + 3] = bb.w;
        }
#pragma unroll
        for (int c = 0; c < 64; ++c) {
            float a = h2[c];
            const float4* w = reinterpret_cast<const float4*>(W3 + (size_t)c * 128 + ch * 32);
#pragma unroll
            for (int j4 = 0; j4 < 8; ++j4) {
                float4 ww = w[j4];
                acc[j4 * 4 + 0] += a * ww.x;
                acc[j4 * 4 + 1] += a * ww.y;
                acc[j4 * 4 + 2] += a * ww.z;
                acc[j4 * 4 + 3] += a * ww.w;
            }
        }
#pragma unroll
        for (int j = 0; j < 32; ++j) {
            float v = fmaxf(acc[j], 0.0f);
#pragma unroll
            for (int m = 16; m >= 1; m >>= 1) v = fmaxf(v, __shfl_xor(v, m, 64));
            acc[j] = v;
        }
        if (k == 0) {
#pragma unroll
            for (int j = 0; j < 32; ++j)
                outF[obase + (size_t)(ch * 32 + j) * NPOINT] = acc[j];
        }
    }
}

// ---------------------------------------------------------------------------
extern "C" void kernel_launch(void* const* d_in, const int* in_sizes, int n_in,
                              void* d_out, int out_size, void* d_ws, size_t ws_size,
                              hipStream_t stream) {
    const float* xyz      = (const float*)d_in[0];
    const float* features = (const float*)d_in[1];
    const float* W1       = (const float*)d_in[2];
    const float* b1       = (const float*)d_in[3];
    const float* W2       = (const float*)d_in[4];
    const float* b2       = (const float*)d_in[5];
    const float* W3       = (const float*)d_in[6];
    const float* b3       = (const float*)d_in[7];

    float* out_newxyz = (float*)d_out;                                  // B*NPOINT*3 f32
    float* out_feat   = (float*)d_out + (size_t)BATCH * NPOINT * 3;     // B*128*NPOINT f32

    // workspace: ballidx 2MB | F1 16.8MB
    int*   ballidx = (int*)d_ws;
    float* F1      = (float*)((char*)d_ws + (size_t)BATCH * NPOINT * NSAMPLE * 4);

    f1_kernel<<<(BATCH * NPTS) / 256, 256, 0, stream>>>(features, W1, F1);

    fps_kernel<<<BATCH, 512, 3 * NPTS * 4, stream>>>(xyz, out_newxyz);

    ball_kernel<<<dim3(NPOINT / 256, BATCH), 256, 3 * NPTS * 4, stream>>>(xyz, out_newxyz, ballidx);

    mlp_kernel<<<(BATCH * NPOINT) / 8, 256, 0, stream>>>(
        xyz, W1, b1, W2, b2, W3, b3, F1, ballidx, out_newxyz, out_feat);
}

// Round 7
// 3360.404 us; speedup vs baseline: 1.9681x; 1.0001x over previous
//
#include <hip/hip_runtime.h>
#include <cstddef>

#define BATCH 8
#define NPTS 8192
#define NFEAT 64
#define NPOINT 2048
#define NSAMPLE 32

// -- plain-rounded ops, contraction-proof (hipcc defaults -ffp-contract=fast;
//    asm blocks mul->fma fusion, matching numpy's non-FMA ufuncs)
__device__ __forceinline__ float sq_nc(float a) {
    float r = a * a;
    asm volatile("" : "+v"(r));
    return r;
}
__device__ __forceinline__ float mul_nc(float a, float b) {
    float r = a * b;
    asm volatile("" : "+v"(r));
    return r;
}
// packed fp32 (2 lanes of plain-rn add/mul per inst — rounding identical to
// v_add_f32/v_mul_f32, so FPS stays bit-exact vs the np reference)
__device__ __forceinline__ float2 pk_add(float2 a, float2 b) {
    float2 r;
    asm("v_pk_add_f32 %0, %1, %2" : "=v"(r) : "v"(a), "v"(b));
    return r;
}
__device__ __forceinline__ float2 pk_mul(float2 a, float2 b) {
    float2 r;
    asm("v_pk_mul_f32 %0, %1, %2" : "=v"(r) : "v"(a), "v"(b));
    return r;
}

// ---------------------------------------------------------------------------
// FPS: one block per batch, 512 threads, 16 points/thread in registers.
// d = (dx*dx + dy*dy) + dz*dz, plain rounded (verified bit-exact R4/R5/R6),
// computed 2 points/inst via v_pk ops; dx = mx + (-xl) (pk_add, exact same
// rounding as sub). Value-only running max in-loop; index recovered by
// reverse equality scan (smallest local j). Tie-break across threads:
// packed u64 (bits(v)<<32)|~idx max-reduction == smallest global idx.
// ONE barrier per iteration (parity double-buffered reduction scratch).
// ---------------------------------------------------------------------------
__global__ __launch_bounds__(512) void fps_kernel(const float* __restrict__ xyz,
                                                  float* __restrict__ newxyz) {
    extern __shared__ float4 sp[];                       // 8192 float4 = 128KB
    __shared__ alignas(16) unsigned long long redp[2][8];

    const int b = blockIdx.x;
    const int tid = threadIdx.x;
    const int lane = tid & 63;
    const int wid = tid >> 6;
    const float* xb = xyz + (size_t)b * NPTS * 3;

    for (int i = tid; i < NPTS; i += 512)
        sp[i] = make_float4(xb[i * 3 + 0], xb[i * 3 + 1], xb[i * 3 + 2], 0.0f);
    __syncthreads();

    // per-thread register tiles, 2 points per float2 slot
    float2 mx2[8], my2[8], mz2[8], md2[8];
    const int base = tid * 16;
#pragma unroll
    for (int j = 0; j < 8; ++j) {
        float4 p0 = sp[base + 2 * j];
        float4 p1 = sp[base + 2 * j + 1];
        mx2[j] = make_float2(p0.x, p1.x);
        my2[j] = make_float2(p0.y, p1.y);
        mz2[j] = make_float2(p0.z, p1.z);
        md2[j] = make_float2(INFINITY, INFINITY);
        asm volatile("" : "+v"(mx2[j]), "+v"(my2[j]), "+v"(mz2[j]));  // pin in VGPRs
    }

    float4 c0 = sp[0];
    if (tid == 0) {
        newxyz[(size_t)b * NPOINT * 3 + 0] = c0.x;
        newxyz[(size_t)b * NPOINT * 3 + 1] = c0.y;
        newxyz[(size_t)b * NPOINT * 3 + 2] = c0.z;
    }
    float xl = c0.x, yl = c0.y, zl = c0.z;
    int par = 0;

    for (int it = 1; it < NPOINT; ++it) {
        const float2 nx = make_float2(-xl, -xl);
        const float2 ny = make_float2(-yl, -yl);
        const float2 nz = make_float2(-zl, -zl);
        float2 bv2 = make_float2(-1.0f, -1.0f);
#pragma unroll
        for (int j = 0; j < 8; ++j) {
            float2 dx = pk_add(mx2[j], nx);
            float2 dy = pk_add(my2[j], ny);
            float2 dz = pk_add(mz2[j], nz);
            float2 d = pk_add(pk_add(pk_mul(dx, dx), pk_mul(dy, dy)), pk_mul(dz, dz));
            md2[j].x = fminf(md2[j].x, d.x);
            md2[j].y = fminf(md2[j].y, d.y);
            bv2.x = fmaxf(bv2.x, md2[j].x);
            bv2.y = fmaxf(bv2.y, md2[j].y);
        }
        const float bv = fmaxf(bv2.x, bv2.y);
        // smallest local j with md==bv (descending scan, last write wins)
        int li = 0;
#pragma unroll
        for (int j = 15; j >= 0; --j) {
            float v = (j & 1) ? md2[j >> 1].y : md2[j >> 1].x;
            li = (v == bv) ? j : li;
        }
        unsigned long long pk =
            ((unsigned long long)__float_as_uint(bv) << 32) |
            (unsigned int)(~(unsigned int)(base + li));
#pragma unroll
        for (int m = 1; m < 64; m <<= 1) {
            unsigned long long o = __shfl_xor(pk, m, 64);
            pk = (o > pk) ? o : pk;
        }
        if (lane == 0) redp[par][wid] = pk;
        __syncthreads();

        const ulonglong2* rp = (const ulonglong2*)redp[par];
        ulonglong2 r0 = rp[0], r1 = rp[1], r2 = rp[2], r3 = rp[3];
        unsigned long long m0 = (r0.x > r0.y) ? r0.x : r0.y;
        unsigned long long m1 = (r1.x > r1.y) ? r1.x : r1.y;
        unsigned long long m2 = (r2.x > r2.y) ? r2.x : r2.y;
        unsigned long long m3 = (r3.x > r3.y) ? r3.x : r3.y;
        m0 = (m1 > m0) ? m1 : m0;
        m2 = (m3 > m2) ? m3 : m2;
        m0 = (m2 > m0) ? m2 : m0;
        const int fi = (int)(~(unsigned int)m0);

        float4 cc = sp[fi];
        xl = cc.x; yl = cc.y; zl = cc.z;
        if (tid == 0) {
            size_t o = (size_t)b * NPOINT * 3 + (size_t)it * 3;
            newxyz[o + 0] = xl;
            newxyz[o + 1] = yl;
            newxyz[o + 2] = zl;
        }
        par ^= 1;
    }
}

// ---------------------------------------------------------------------------
// Ball query: first NSAMPLE indices (ascending) with d2 < 0.04f (strict f32).
// d2 = (cq + sq) - 2*dot; cq/sq plain (verified R5/R6; sq precomputed at
// staging, bit-identical formula); dot = FMA chain fma(cz,z,fma(cy,y,cx*x)).
// Break-free full scan (pipelinable LDS reads); 1 wave/block, 256 blocks.
// ---------------------------------------------------------------------------
__global__ __launch_bounds__(64) void ball_kernel(const float* __restrict__ xyz,
                                                  const float* __restrict__ newxyz,
                                                  int* __restrict__ ballidx) {
    extern __shared__ float4 s4[];                       // 8192 float4 = 128KB
    const int b = blockIdx.y;
    const int s = blockIdx.x * 64 + threadIdx.x;
    const float* xb = xyz + (size_t)b * NPTS * 3;
    for (int i = threadIdx.x; i < NPTS; i += 64) {
        float x = xb[i * 3 + 0], y = xb[i * 3 + 1], z = xb[i * 3 + 2];
        float sq = (sq_nc(x) + sq_nc(y)) + sq_nc(z);
        s4[i] = make_float4(x, y, z, sq);
    }
    __syncthreads();

    const int sIdx = b * NPOINT + s;
    float cx = newxyz[(size_t)sIdx * 3 + 0];
    float cy = newxyz[(size_t)sIdx * 3 + 1];
    float cz = newxyz[(size_t)sIdx * 3 + 2];
    float cq = (sq_nc(cx) + sq_nc(cy)) + sq_nc(cz);

    int* ob = ballidx + (size_t)sIdx * NSAMPLE;
    int cnt = 0;
    int first = 0;
#pragma unroll 4
    for (int n = 0; n < NPTS; ++n) {
        float4 p = s4[n];
        float dot = __fmaf_rn(cz, p.z, __fmaf_rn(cy, p.y, __fmul_rn(cx, p.x)));
        float d2 = (cq + p.w) - mul_nc(2.0f, dot);
        if (d2 < 0.04f && cnt < NSAMPLE) {
            ob[cnt] = n;
            if (cnt == 0) first = n;
            ++cnt;
        }
    }
    for (int j = cnt; j < NSAMPLE; ++j) ob[j] = first;
}

// ---------------------------------------------------------------------------
// F1 precompute: F1[b,n,c] = sum_{c'} features[b,c',n] * W1[3+c', c]
// Wave = one 16-channel chunk for 64 consecutive points (coalesced feat).
// ---------------------------------------------------------------------------
__global__ __launch_bounds__(256) void f1_kernel(const float* __restrict__ features,
                                                 const float* __restrict__ W1,
                                                 float* __restrict__ F1) {
    const int lane = threadIdx.x & 63;
    const int chunk = threadIdx.x >> 6;                // 0..3
    const int blk = blockIdx.x;                        // 0..1023
    const int b = blk >> 7;
    const int n = ((blk & 127) << 6) | lane;
    const float* fb = features + (size_t)b * NFEAT * NPTS + n;
    const float* wbase = W1 + 3 * 64 + chunk * 16;

    float acc[16];
#pragma unroll
    for (int i = 0; i < 16; ++i) acc[i] = 0.0f;

#pragma unroll 4
    for (int cp = 0; cp < 64; ++cp) {
        float f = fb[(size_t)cp * NPTS];
        const float4* w = reinterpret_cast<const float4*>(wbase + (size_t)cp * 64);
#pragma unroll
        for (int c4 = 0; c4 < 4; ++c4) {
            float4 ww = w[c4];
            acc[c4 * 4 + 0] += f * ww.x;
            acc[c4 * 4 + 1] += f * ww.y;
            acc[c4 * 4 + 2] += f * ww.z;
            acc[c4 * 4 + 3] += f * ww.w;
        }
    }
    float* o = F1 + ((size_t)b * NPTS + n) * 64 + chunk * 16;
#pragma unroll
    for (int c4 = 0; c4 < 4; ++c4) {
        float4 v;
        v.x = acc[c4 * 4 + 0]; v.y = acc[c4 * 4 + 1];
        v.z = acc[c4 * 4 + 2]; v.w = acc[c4 * 4 + 3];
        *reinterpret_cast<float4*>(o + c4 * 4) = v;
    }
}

// ---------------------------------------------------------------------------
// Fused grouped-MLP + max-pool. 256 threads = 8 centers x 32 samples.
// h staged in static LDS [64][256] per-thread-column (conflict-free, no
// barriers: each thread touches only its own column). c-loops ROLLED
// (unroll 4) to keep code << I-cache; weights via wave-uniform loads.
// ---------------------------------------------------------------------------
__global__ __launch_bounds__(256) void mlp_kernel(const float* __restrict__ xyz,
                                                  const float* __restrict__ W1,
                                                  const float* __restrict__ b1,
                                                  const float* __restrict__ W2,
                                                  const float* __restrict__ b2,
                                                  const float* __restrict__ W3,
                                                  const float* __restrict__ b3,
                                                  const float* __restrict__ F1,
                                                  const int* __restrict__ ballidx,
                                                  const float* __restrict__ newxyz,
                                                  float* __restrict__ outF) {
    __shared__ float hbuf[64][256];                    // 64KB static
    const int tid = threadIdx.x;
    const int k = tid & 31;
    const int sIdx = blockIdx.x * 8 + (tid >> 5);      // 0 .. BATCH*NPOINT-1
    const int b = sIdx >> 11;
    const int s = sIdx & (NPOINT - 1);

    const int p = ballidx[(size_t)sIdx * NSAMPLE + k];
    const float* xb = xyz + (size_t)b * NPTS * 3;
    float rx = xb[p * 3 + 0] - newxyz[(size_t)sIdx * 3 + 0];
    float ry = xb[p * 3 + 1] - newxyz[(size_t)sIdx * 3 + 1];
    float rz = xb[p * 3 + 2] - newxyz[(size_t)sIdx * 3 + 2];

    // ---- layer 1 -> LDS column
    const float* f1p = F1 + ((size_t)b * NPTS + p) * 64;
#pragma unroll 4
    for (int c4 = 0; c4 < 16; ++c4) {
        float4 f  = *reinterpret_cast<const float4*>(f1p + c4 * 4);
        float4 wx = *reinterpret_cast<const float4*>(W1 + c4 * 4);
        float4 wy = *reinterpret_cast<const float4*>(W1 + 64 + c4 * 4);
        float4 wz = *reinterpret_cast<const float4*>(W1 + 128 + c4 * 4);
        float4 bb = *reinterpret_cast<const float4*>(b1 + c4 * 4);
        hbuf[c4 * 4 + 0][tid] = fmaxf(bb.x + f.x + rx * wx.x + ry * wy.x + rz * wz.x, 0.0f);
        hbuf[c4 * 4 + 1][tid] = fmaxf(bb.y + f.y + rx * wx.y + ry * wy.y + rz * wz.y, 0.0f);
        hbuf[c4 * 4 + 2][tid] = fmaxf(bb.z + f.z + rx * wx.z + ry * wy.z + rz * wz.z, 0.0f);
        hbuf[c4 * 4 + 3][tid] = fmaxf(bb.w + f.w + rx * wx.w + ry * wy.w + rz * wz.w, 0.0f);
    }

    // ---- layer 2: h2 in regs, h1 read from LDS
    float h2[64];
#pragma unroll
    for (int d4 = 0; d4 < 16; ++d4) {
        float4 bb = *reinterpret_cast<const float4*>(b2 + d4 * 4);
        h2[d4 * 4 + 0] = bb.x; h2[d4 * 4 + 1] = bb.y;
        h2[d4 * 4 + 2] = bb.z; h2[d4 * 4 + 3] = bb.w;
    }
#pragma unroll 4
    for (int c = 0; c < 64; ++c) {
        float a = hbuf[c][tid];
        const float4* w = reinterpret_cast<const float4*>(W2 + (size_t)c * 64);
#pragma unroll
        for (int d4 = 0; d4 < 16; ++d4) {
            float4 ww = w[d4];
            h2[d4 * 4 + 0] += a * ww.x;
            h2[d4 * 4 + 1] += a * ww.y;
            h2[d4 * 4 + 2] += a * ww.z;
            h2[d4 * 4 + 3] += a * ww.w;
        }
    }
    // relu + restage into same LDS columns (h1 dead; own column -> no barrier)
#pragma unroll
    for (int d = 0; d < 64; ++d) hbuf[d][tid] = fmaxf(h2[d], 0.0f);

    // ---- layer 3 + relu + max over 32 samples, 4 chunks of 32 channels
    const size_t obase = (size_t)b * 128 * NPOINT + s;
#pragma unroll 1
    for (int ch = 0; ch < 4; ++ch) {
        float acc[32];
#pragma unroll
        for (int j4 = 0; j4 < 8; ++j4) {
            float4 bb = *reinterpret_cast<const float4*>(b3 + ch * 32 + j4 * 4);
            acc[j4 * 4 + 0] = bb.x; acc[j4 * 4 + 1] = bb.y;
            acc[j4 * 4 + 2] = bb.z; acc[j4 * 4 + 3] = bb.w;
        }
#pragma unroll 4
        for (int c = 0; c < 64; ++c) {
            float a = hbuf[c][tid];
            const float4* w = reinterpret_cast<const float4*>(W3 + (size_t)c * 128 + ch * 32);
#pragma unroll
            for (int j4 = 0; j4 < 8; ++j4) {
                float4 ww = w[j4];
                acc[j4 * 4 + 0] += a * ww.x;
                acc[j4 * 4 + 1] += a * ww.y;
                acc[j4 * 4 + 2] += a * ww.z;
                acc[j4 * 4 + 3] += a * ww.w;
            }
        }
#pragma unroll
        for (int j = 0; j < 32; ++j) {
            float v = fmaxf(acc[j], 0.0f);
#pragma unroll
            for (int m = 16; m >= 1; m >>= 1) v = fmaxf(v, __shfl_xor(v, m, 64));
            acc[j] = v;
        }
        if (k == 0) {
#pragma unroll
            for (int j = 0; j < 32; ++j)
                outF[obase + (size_t)(ch * 32 + j) * NPOINT] = acc[j];
        }
    }
}

// ---------------------------------------------------------------------------
extern "C" void kernel_launch(void* const* d_in, const int* in_sizes, int n_in,
                              void* d_out, int out_size, void* d_ws, size_t ws_size,
                              hipStream_t stream) {
    const float* xyz      = (const float*)d_in[0];
    const float* features = (const float*)d_in[1];
    const float* W1       = (const float*)d_in[2];
    const float* b1       = (const float*)d_in[3];
    const float* W2       = (const float*)d_in[4];
    const float* b2       = (const float*)d_in[5];
    const float* W3       = (const float*)d_in[6];
    const float* b3       = (const float*)d_in[7];

    float* out_newxyz = (float*)d_out;                                  // B*NPOINT*3 f32
    float* out_feat   = (float*)d_out + (size_t)BATCH * NPOINT * 3;     // B*128*NPOINT f32

    // workspace: ballidx 2MB | F1 16.8MB
    int*   ballidx = (int*)d_ws;
    float* F1      = (float*)((char*)d_ws + (size_t)BATCH * NPOINT * NSAMPLE * 4);

    f1_kernel<<<1024, 256, 0, stream>>>(features, W1, F1);

    fps_kernel<<<BATCH, 512, NPTS * 16, stream>>>(xyz, out_newxyz);

    ball_kernel<<<dim3(NPOINT / 64, BATCH), 64, NPTS * 16, stream>>>(xyz, out_newxyz, ballidx);

    mlp_kernel<<<(BATCH * NPOINT) / 8, 256, 0, stream>>>(
        xyz, W1, b1, W2, b2, W3, b3, F1, ballidx, out_newxyz, out_feat);
}